// Round 5
// baseline (242.842 us; speedup 1.0000x reference)
//
#include <hip/hip_runtime.h>
#include <math.h>

// ---------------- problem constants ----------------
#define BATCH   256
#define SIGLEN  2048
#define L1OUT   1022   // conv1(2046) -> pool k3 s2
#define L2OUT   339    // conv2(1018) -> pool k3 s3
#define L3OUT   168    // conv3(337)  -> pool k3 s2
#define FCIN    10752  // 64*168

// conv12 tiling: wave = co-tile, 3 pos-tiles, 16x16x32; TP2=16 -> 28.3 KB LDS -> 5 blocks/CU
#define TP2   16
#define NROW  52             // 48 positions + 4 halo
#define H1S   136            // row stride (shorts): 272B rows -> ds_read_b128
#define H1SZ  (NROW*H1S)     // 7072 shorts = 14144 B per plane

// tail kernel: whole-signal conv3 staging, 346 rows x 72 shorts per plane
#define H3R   346

typedef float f32x2  __attribute__((ext_vector_type(2)));
typedef float f32x4  __attribute__((ext_vector_type(4)));
typedef short s16x8  __attribute__((ext_vector_type(8)));

__device__ __forceinline__ unsigned short f2bf(float f) {
    unsigned int u = __float_as_uint(f);
    return (unsigned short)((u + 0x7fffu + ((u >> 16) & 1u)) >> 16);
}
__device__ __forceinline__ float bf2f(unsigned short h) {
    return __uint_as_float(((unsigned int)h) << 16);
}
// packed fp32 FMA (CDNA2+ VOP3P): d = a*b + c on both halves
__device__ __forceinline__ f32x2 pkfma(f32x2 a, f32x2 b, f32x2 c) {
    f32x2 d;
    asm("v_pk_fma_f32 %0, %1, %2, %3" : "=v"(d) : "v"(a), "v"(b), "v"(c));
    return d;
}

// ---------------- prep: weight frag splits + fc1 LDS-transpose permute + BN fold ----------------
__launch_bounds__(256)
__global__ void prep_kernel(
    const float* __restrict__ conv1_b,
    const float* __restrict__ g1, const float* __restrict__ b1,
    const float* __restrict__ m1, const float* __restrict__ v1,
    const float* __restrict__ conv2_w, const float* __restrict__ conv2_b,
    const float* __restrict__ g2, const float* __restrict__ b2,
    const float* __restrict__ m2, const float* __restrict__ v2,
    const float* __restrict__ conv3_w, const float* __restrict__ conv3_b,
    const float* __restrict__ g3, const float* __restrict__ b3,
    const float* __restrict__ m3, const float* __restrict__ v3,
    const float* __restrict__ fc1_w,
    unsigned short* __restrict__ w2hi, unsigned short* __restrict__ w2lo,
    unsigned short* __restrict__ w3hi, unsigned short* __restrict__ w3lo,
    float* __restrict__ wp1,
    float* __restrict__ so1, float* __restrict__ so2, float* __restrict__ so3)
{
    __shared__ float tl[64 * 169];   // transpose tile, stride 169 breaks conflicts

    int t   = threadIdx.x;
    int tid = blockIdx.x * 256 + t;
    int stride = gridDim.x * 256;

    // fc1 permute via LDS: block o (<48) transposes fc1_w[o] (64co x 168u) -> wp1[o][u*64+co]
    if (blockIdx.x < 48) {
        int o = blockIdx.x;
        for (int i = t; i < FCIN; i += 256) {
            int co = i / L3OUT, u = i - co * L3OUT;
            tl[co * 169 + u] = fc1_w[o * FCIN + i];      // coalesced read
        }
        __syncthreads();
        for (int i = t; i < FCIN; i += 256) {
            int u = i >> 6, co = i & 63;
            wp1[o * FCIN + i] = tl[co * 169 + u];        // coalesced write
        }
    }

    // W2 frag (16x16x32): dst = ((k*4 + ci>>5)*64 + co)*32 + (ci&31)
    for (int i = tid; i < 64*128*5; i += stride) {
        int co = i / 640; int rr = i - co*640; int ci = rr / 5; int k = rr - ci*5;
        float w = conv2_w[i];
        unsigned short hi = f2bf(w);
        unsigned short lo = f2bf(w - bf2f(hi));
        int dst = ((k*4 + (ci >> 5))*64 + co)*32 + (ci & 31);
        w2hi[dst] = hi;
        w2lo[dst] = lo;
    }
    // W3 frag (16x16x32): seg s = k*2 + (ci>>5); dst = (s*64 + co)*32 + (ci&31)
    for (int i = tid; i < 64*64*3; i += stride) {
        int co = i / 192; int r = i - co*192; int ci = r / 3; int k = r - ci*3;
        float w = conv3_w[i];
        unsigned short hi = f2bf(w);
        unsigned short lo = f2bf(w - bf2f(hi));
        int dst = ((k*2 + (ci >> 5))*64 + co)*32 + (ci & 31);
        w3hi[dst] = hi;
        w3lo[dst] = lo;
    }
    if (tid < 128) {
        float s = g1[tid] / sqrtf(v1[tid] + 1e-5f);
        so1[tid]       = s;
        so1[128 + tid] = (conv1_b[tid] - m1[tid]) * s + b1[tid];
    }
    if (tid < 64) {
        float s2 = g2[tid] / sqrtf(v2[tid] + 1e-5f);
        so2[tid]      = s2;
        so2[64 + tid] = (conv2_b[tid] - m2[tid]) * s2 + b2[tid];
        float s3 = g3[tid] / sqrtf(v3[tid] + 1e-5f);
        so3[tid]      = s3;
        so3[64 + tid] = (conv3_b[tid] - m3[tid]) * s3 + b3[tid];
    }
}

// ---------------- fused conv1(pk_fma + carry) -> conv2 split-bf16 MFMA ----------------
// (unchanged from round 4 — best measured: ~91 us)
__launch_bounds__(256, 5)
__global__ void conv12_kernel(
    const float* __restrict__ x, const float* __restrict__ w1,
    const unsigned short* __restrict__ w2hi, const unsigned short* __restrict__ w2lo,
    const float* __restrict__ so1, const float* __restrict__ so2,
    unsigned int* __restrict__ h2p)
{
    __shared__ unsigned short h1hi[H1SZ];   // 14144 B; c2 (12480 B) aliases after K-loop
    __shared__ unsigned short h1lo[H1SZ];

    int t  = threadIdx.x;
    int b  = blockIdx.x;
    int u0 = blockIdx.y * TP2;
    int q0 = 3 * u0;
    int wv = __builtin_amdgcn_readfirstlane(t >> 6);
    int l  = t & 63;
    int m  = l & 15;
    int qd = l >> 4;

    // ---- stage 1: conv1 + bn1 + pool + relu, channel-paired pk_fma, carried window ----
    {
        f32x2 wp[9], s1p, o1p;
        const float* wa = w1 + (2*l)*9;
        #pragma unroll
        for (int j = 0; j < 9; ++j) wp[j] = (f32x2){wa[j], wa[9 + j]};
        s1p = (f32x2){so1[2*l], so1[2*l + 1]};
        o1p = (f32x2){so1[128 + 2*l], so1[128 + 2*l + 1]};

        int rbase = 13 * wv;                  // 0,13,26,39 (52 rows total)
        int W0 = 2*(q0 + rbase);              // x window start for first row
        const float* xp0 = x + b*3*SIGLEN;

        f32x2 xb[3][6];                       // broadcast pairs covering [W0 .. W0+5]
        if (W0 + 5 <= SIGLEN - 1) {           // wave-uniform fast path, 8B-aligned
            #pragma unroll
            for (int ci = 0; ci < 3; ++ci) {
                const float* xp = xp0 + ci*SIGLEN + W0;
                float2 v01 = *(const float2*)(xp);
                float2 v23 = *(const float2*)(xp + 2);
                float2 v45 = *(const float2*)(xp + 4);
                xb[ci][0] = (f32x2){v01.x, v01.x};
                xb[ci][1] = (f32x2){v01.y, v01.y};
                xb[ci][2] = (f32x2){v23.x, v23.x};
                xb[ci][3] = (f32x2){v23.y, v23.y};
                xb[ci][4] = (f32x2){v45.x, v45.x};
                xb[ci][5] = (f32x2){v45.y, v45.y};
            }
        } else {
            #pragma unroll
            for (int ci = 0; ci < 3; ++ci)
                #pragma unroll
                for (int j = 0; j < 6; ++j) {
                    int xi = W0 + j; xi = xi < SIGLEN ? xi : SIGLEN - 1;
                    float v = xp0[ci*SIGLEN + xi];
                    xb[ci][j] = (f32x2){v, v};
                }
        }

        f32x2 cr = (f32x2){0.f, 0.f};
        #pragma unroll
        for (int s = 0; s < 13; ++s) {
            int r = rbase + s;
            f32x2 r1 = (f32x2){0.f, 0.f}, r2 = (f32x2){0.f, 0.f};
            #pragma unroll
            for (int ci = 0; ci < 3; ++ci) {
                #pragma unroll
                for (int tp = 0; tp < 3; ++tp) {
                    r1 = pkfma(xb[ci][1 + tp], wp[ci*3 + tp], r1);
                    r2 = pkfma(xb[ci][2 + tp], wp[ci*3 + tp], r2);
                }
            }
            f32x2 r0;
            if (s == 0) {
                r0 = (f32x2){0.f, 0.f};
                #pragma unroll
                for (int ci = 0; ci < 3; ++ci)
                    #pragma unroll
                    for (int tp = 0; tp < 3; ++tp)
                        r0 = pkfma(xb[ci][tp], wp[ci*3 + tp], r0);
            } else {
                r0 = cr;
            }
            cr = r2;

            float m0 = fmaxf(r0[0], fmaxf(r1[0], r2[0]));
            float m1 = fmaxf(r0[1], fmaxf(r1[1], r2[1]));
            float v0 = fmaxf(fmaf(s1p[0], m0, o1p[0]), 0.f);
            float v1 = fmaxf(fmaf(s1p[1], m1, o1p[1]), 0.f);

            // truncation split: hi = top16(v), lo = rne16(v - hi); perm-packed b32 writes.
            unsigned ua = __float_as_uint(v0);
            unsigned ub = __float_as_uint(v1);
            unsigned hipack = __builtin_amdgcn_perm(ub, ua, 0x07060302u);
            float ra = v0 - __uint_as_float(ua & 0xffff0000u);
            float rb = v1 - __uint_as_float(ub & 0xffff0000u);
            unsigned lopack = __builtin_amdgcn_perm(__float_as_uint(rb), __float_as_uint(ra),
                                                    0x07060302u);
            ((unsigned*)h1hi)[r*68 + l] = hipack;   // dword at short-cols {2l, 2l+1}
            ((unsigned*)h1lo)[r*68 + l] = lopack;

            if (s < 12) {
                #pragma unroll
                for (int ci = 0; ci < 3; ++ci) {
                    xb[ci][0] = xb[ci][2]; xb[ci][1] = xb[ci][3];
                    xb[ci][2] = xb[ci][4]; xb[ci][3] = xb[ci][5];
                }
                int Wn = W0 + 2*s + 6;
                if (Wn + 1 <= SIGLEN - 1) {         // wave-uniform, 8B-aligned
                    #pragma unroll
                    for (int ci = 0; ci < 3; ++ci) {
                        float2 v = *(const float2*)(xp0 + ci*SIGLEN + Wn);
                        xb[ci][4] = (f32x2){v.x, v.x};
                        xb[ci][5] = (f32x2){v.y, v.y};
                    }
                } else {
                    #pragma unroll
                    for (int ci = 0; ci < 3; ++ci) {
                        int x4 = Wn     < SIGLEN ? Wn     : SIGLEN - 1;
                        int x5 = Wn + 1 < SIGLEN ? Wn + 1 : SIGLEN - 1;
                        float a4 = xp0[ci*SIGLEN + x4];
                        float a5 = xp0[ci*SIGLEN + x5];
                        xb[ci][4] = (f32x2){a4, a4};
                        xb[ci][5] = (f32x2){a5, a5};
                    }
                }
            }
        }
    }
    __syncthreads();

    // ---- stage 2: 16x16x32 MFMA, wave owns co-tile wv, 3 pos-tiles ----
    f32x4 acc[3] = {(f32x4)(0.f), (f32x4)(0.f), (f32x4)(0.f)};

    const unsigned short* whb = w2hi + wv*512 + m*32 + qd*8;
    const unsigned short* wlb = w2lo + wv*512 + m*32 + qd*8;

    for (int k = 0; k < 5; ++k) {
        #pragma unroll
        for (int cb = 0; cb < 4; ++cb) {
            int st = k*4 + cb;
            s16x8 wh = *(const s16x8*)(whb + st*2048);
            s16x8 wl = *(const s16x8*)(wlb + st*2048);
            #pragma unroll
            for (int pt = 0; pt < 3; ++pt) {
                int row = pt*16 + m + k;   // <= 51
                s16x8 ah = *(const s16x8*)&h1hi[row*H1S + cb*32 + qd*8];
                s16x8 al = *(const s16x8*)&h1lo[row*H1S + cb*32 + qd*8];
                acc[pt] = __builtin_amdgcn_mfma_f32_16x16x32_bf16(ah, wh, acc[pt], 0, 0, 0);
                acc[pt] = __builtin_amdgcn_mfma_f32_16x16x32_bf16(al, wh, acc[pt], 0, 0, 0);
                acc[pt] = __builtin_amdgcn_mfma_f32_16x16x32_bf16(ah, wl, acc[pt], 0, 0, 0);
            }
        }
    }
    __syncthreads();   // all waves done reading h1hi before aliasing as c2

    // D layout: pos = pt*16 + qd*4 + rg, co = wv*16 + m
    float* c2 = (float*)h1hi;   // [48 pos][65]
    #pragma unroll
    for (int pt = 0; pt < 3; ++pt)
        #pragma unroll
        for (int rg = 0; rg < 4; ++rg)
            c2[(pt*16 + qd*4 + rg)*65 + wv*16 + m] = acc[pt][rg];
    __syncthreads();

    // ---- pool(3,3) + bn2 + relu -> h2p[b][u][co] packed bf16 hi|lo (trunc split) ----
    #pragma unroll
    for (int it = 0; it < 4; ++it) {
        int idx = t + it*256;   // < TP2*64 = 1024
        int ul = idx >> 6, co = idx & 63;
        int u = u0 + ul;
        if (u < L2OUT) {
            float v0 = c2[(3*ul  )*65 + co];
            float v1 = c2[(3*ul+1)*65 + co];
            float v2 = c2[(3*ul+2)*65 + co];
            float mm = fmaxf(v0, fmaxf(v1, v2));
            float v  = fmaxf(fmaf(so2[co], mm, so2[64 + co]), 0.f);
            unsigned uu = __float_as_uint(v);
            float rr = v - __uint_as_float(uu & 0xffff0000u);
            h2p[(b*L2OUT + u)*64 + co] = (uu >> 16) | (__float_as_uint(rr) & 0xffff0000u);
        }
    }
}

// ---------------- fused tail: conv3 + pool + bn3 + fc1..fc4 + tanh + integrate + interp ----------------
// One block per batch item (grid 256 = 1 block/CU). 512 thr = 8 waves.
// Whole h2p[b] staged in LDS once; fc1 partials accumulate in registers across all 6 tiles;
// fc chain computed once; 2048 warp points (4/thread).
__launch_bounds__(512, 1)
__global__ void tail_kernel(
    const unsigned int* __restrict__ h2p,
    const unsigned short* __restrict__ w3hi, const unsigned short* __restrict__ w3lo,
    const float* __restrict__ so3, const float* __restrict__ wp1,
    const float* __restrict__ fc1_b,
    const float* __restrict__ fc2_w, const float* __restrict__ fc2_b,
    const float* __restrict__ fc3_w, const float* __restrict__ fc3_b,
    const float* __restrict__ fc4_w, const float* __restrict__ fc4_b,
    const float* __restrict__ basis,
    const float* __restrict__ x,
    float* __restrict__ out)
{
    __shared__ unsigned short h3s[2*H3R*72];   // hi plane | lo plane (99.6 KB)
    __shared__ float c3buf[64*65];             // 16.6 KB
    __shared__ float xsr[48];
    __shared__ float xs48[48], hl[32], gl[16], thl[5], Al[12];

    int t  = threadIdx.x;
    int b  = blockIdx.x;
    int wv = __builtin_amdgcn_readfirstlane(t >> 6);   // 0..7
    int l  = t & 63;
    int m  = l & 15;
    int qd = l >> 4;
    int hh = wv >> 2;          // pt-pair group
    int c4 = wv & 3;           // co-quarter

    // ---- stage whole signal: h2p[b] -> hi/lo planes, rows clamped at 338 ----
    for (int i = t; i < H3R*64; i += 512) {
        int r = i >> 6, ci = i & 63;
        int g = r > (L2OUT-1) ? (L2OUT-1) : r;
        unsigned int v = h2p[(b*L2OUT + g)*64 + ci];
        h3s[r*72 + ci]           = (unsigned short)(v & 0xffffu);
        h3s[H3R*72 + r*72 + ci]  = (unsigned short)(v >> 16);
    }

    // conv3 weight frags for this wave's co-quarter (held in regs throughout)
    s16x8 wh[6], wl[6];
    #pragma unroll
    for (int s = 0; s < 6; ++s) {
        wh[s] = *(const s16x8*)(w3hi + s*2048 + (c4*16 + m)*32 + qd*8);
        wl[s] = *(const s16x8*)(w3lo + s*2048 + (c4*16 + m)*32 + qd*8);
    }
    float s3 = so3[l], o3 = so3[64 + l];

    __syncthreads();

    // ---- 6 tiles of 28 pooled outputs; fc1 partials accumulate in regs ----
    int o0 = wv * 6;           // wave's fc1 outputs o0..o0+5
    float fa[6];
    #pragma unroll
    for (int j = 0; j < 6; ++j) fa[j] = 0.f;

    for (int ti = 0; ti < 6; ++ti) {
        int u0 = ti * 28;

        // conv3 MFMA: wave (hh,c4) does pt in {2hh, 2hh+1} for co-slice c4
        f32x4 acc[2] = {(f32x4)(0.f), (f32x4)(0.f)};
        #pragma unroll
        for (int pp = 0; pp < 2; ++pp) {
            int pt = 2*hh + pp;
            #pragma unroll
            for (int s = 0; s < 6; ++s) {
                int row = 2*u0 + pt*16 + m + (s >> 1);   // <= 345
                int off = (s & 1)*32 + qd*8;
                s16x8 ah = *(const s16x8*)&h3s[row*72 + off];
                s16x8 al = *(const s16x8*)&h3s[H3R*72 + row*72 + off];
                acc[pp] = __builtin_amdgcn_mfma_f32_16x16x32_bf16(ah, wh[s], acc[pp], 0, 0, 0);
                acc[pp] = __builtin_amdgcn_mfma_f32_16x16x32_bf16(al, wh[s], acc[pp], 0, 0, 0);
                acc[pp] = __builtin_amdgcn_mfma_f32_16x16x32_bf16(ah, wl[s], acc[pp], 0, 0, 0);
            }
        }
        __syncthreads();   // previous tile's c3buf readers done

        #pragma unroll
        for (int pp = 0; pp < 2; ++pp)
            #pragma unroll
            for (int rg = 0; rg < 4; ++rg)
                c3buf[((2*hh + pp)*16 + qd*4 + rg)*65 + c4*16 + m] = acc[pp][rg];
        __syncthreads();

        // pool(3,2) + bn3 + relu + fc1 partial for co = l, u = u0..u0+27
        #pragma unroll 4
        for (int u = 0; u < 28; ++u) {
            int p = 2*u;
            float v0 = c3buf[(p  )*65 + l];
            float v1 = c3buf[(p+1)*65 + l];
            float v2 = c3buf[(p+2)*65 + l];
            float pv = fmaxf(fmaf(s3, fmaxf(v0, fmaxf(v1, v2)), o3), 0.f);
            const float* wp = wp1 + (u0 + u)*64 + l;
            #pragma unroll
            for (int j = 0; j < 6; ++j)
                fa[j] = fmaf(pv, wp[(o0 + j)*FCIN], fa[j]);
        }
    }

    // ---- fc1 reduce (over co lanes) ----
    #pragma unroll
    for (int j = 0; j < 6; ++j) {
        #pragma unroll
        for (int off = 32; off > 0; off >>= 1)
            fa[j] += __shfl_xor(fa[j], off, 64);
    }
    if (l == 0) {
        #pragma unroll
        for (int j = 0; j < 6; ++j) xsr[o0 + j] = fa[j];
    }
    __syncthreads();

    // ---- fc chain (once per batch item) ----
    if (t < 48) xs48[t] = fmaxf(xsr[t] + fc1_b[t], 0.f);
    __syncthreads();
    if (t < 32) {
        float sv = fc2_b[t];
        #pragma unroll
        for (int k = 0; k < 48; ++k) sv = fmaf(fc2_w[t * 48 + k], xs48[k], sv);
        hl[t] = fmaxf(sv, 0.f);
    }
    __syncthreads();
    if (t < 16) {
        float sv = fc3_b[t];
        #pragma unroll
        for (int k = 0; k < 32; ++k) sv = fmaf(fc3_w[t * 32 + k], hl[k], sv);
        gl[t] = fmaxf(sv, 0.f);
    }
    __syncthreads();
    if (t < 5) {
        float sv = fc4_b[t];
        #pragma unroll
        for (int k = 0; k < 16; ++k) sv = fmaf(fc4_w[t * 16 + k], gl[k], sv);
        thl[t] = tanhf(sv);
    }
    __syncthreads();
    if (t < 12) {
        float sv = 0.f;
        #pragma unroll
        for (int d = 0; d < 5; ++d) sv = fmaf(basis[t * 5 + d], thl[d], sv);
        Al[t] = sv;
    }
    __syncthreads();

    float a_r[6], b_r[6];
    #pragma unroll
    for (int c = 0; c < 6; ++c) { a_r[c] = Al[2*c]; b_r[c] = Al[2*c+1]; }

    // ---- CPAB integration + interp: 4 points per thread ----
    #pragma unroll
    for (int cc = 0; cc < 4; ++cc) {
        int i = cc * 512 + t;
        float xp = (float)i / 2047.f;
        float tt = 1.f;
        for (int it = 0; it < 7; ++it) {
            int c = (int)floorf(xp * 6.f);
            c = min(max(c, 0), 5);
            float a  = a_r[c], bb = b_r[c];
            float v  = a * xp + bb;
            float xb = (v >= 0.f) ? (float)(c + 1) / 6.f : (float)c / 6.f;
            bool  big_a = fabsf(a) > 1e-8f;
            float a_s = big_a ? a : 1.f;
            float z   = xp + bb / a_s;
            float zb  = xb + bb / a_s;
            float zden = (fabsf(z) > 1e-12f) ? z : 1e-12f;
            float ratio = zb / zden;
            float t_exp = logf(fmaxf(ratio, 1e-12f)) / a_s;
            float v_s   = (fabsf(v) > 1e-12f) ? v : 1.f;
            float t_lin = (xb - xp) / v_s;
            float thit  = big_a ? t_exp : t_lin;
            bool valid  = (fabsf(v) > 1e-12f) && (thit > 0.f) && ((big_a ? ratio : 1.f) > 0.f);
            if (!valid) thit = __builtin_inff();
            float tau   = fminf(tt, thit);
            float x_new = big_a ? (z * expf(a * tau) - (z - xp)) : (xp + bb * tau);
            bool hit    = (thit <= tt);
            float nudge = (v >= 0.f) ? 1e-6f : -1e-6f;
            xp = hit ? (xb + nudge) : x_new;
            xp = fminf(fmaxf(xp, 0.f), 1.f);
            tt = fmaxf(tt - tau, 0.f);
        }
        float p = fminf(fmaxf(xp, 0.f), 1.f) * 2047.f;
        int i0 = (int)floorf(p);
        i0 = min(max(i0, 0), 2046);
        float w = p - (float)i0;
        #pragma unroll
        for (int c = 0; c < 3; ++c) {
            const float* d = &x[(b * 3 + c) * SIGLEN];
            out[(b * 3 + c) * SIGLEN + i] = d[i0] * (1.f - w) + d[i0 + 1] * w;
        }
    }
}

// ---------------- launch ----------------
extern "C" void kernel_launch(void* const* d_in, const int* in_sizes, int n_in,
                              void* d_out, int out_size, void* d_ws, size_t ws_size,
                              hipStream_t stream) {
    (void)in_sizes; (void)n_in; (void)out_size; (void)ws_size;
    const float* x       = (const float*)d_in[0];
    const float* conv1_w = (const float*)d_in[1];
    const float* conv1_b = (const float*)d_in[2];
    const float* bn1_g   = (const float*)d_in[3];
    const float* bn1_b   = (const float*)d_in[4];
    const float* bn1_m   = (const float*)d_in[5];
    const float* bn1_v   = (const float*)d_in[6];
    const float* conv2_w = (const float*)d_in[7];
    const float* conv2_b = (const float*)d_in[8];
    const float* bn2_g   = (const float*)d_in[9];
    const float* bn2_b   = (const float*)d_in[10];
    const float* bn2_m   = (const float*)d_in[11];
    const float* bn2_v   = (const float*)d_in[12];
    const float* conv3_w = (const float*)d_in[13];
    const float* conv3_b = (const float*)d_in[14];
    const float* bn3_g   = (const float*)d_in[15];
    const float* bn3_b   = (const float*)d_in[16];
    const float* bn3_m   = (const float*)d_in[17];
    const float* bn3_v   = (const float*)d_in[18];
    const float* fc1_w   = (const float*)d_in[19];
    const float* fc1_b   = (const float*)d_in[20];
    const float* fc2_w   = (const float*)d_in[21];
    const float* fc2_b   = (const float*)d_in[22];
    const float* fc3_w   = (const float*)d_in[23];
    const float* fc3_b   = (const float*)d_in[24];
    const float* fc4_w   = (const float*)d_in[25];
    const float* fc4_b   = (const float*)d_in[26];
    const float* basis   = (const float*)d_in[27];

    // workspace layout
    unsigned short* w2hi = (unsigned short*)d_ws;       // 40960 ush
    unsigned short* w2lo = w2hi + 40960;                // 40960 ush
    unsigned short* w3hi = w2lo + 40960;                // 12288 ush
    unsigned short* w3lo = w3hi + 12288;                // 12288 ush
    float* ws   = (float*)d_ws;
    float* so1  = ws + 53248;           // 256
    float* so2  = so1 + 256;            // 128
    float* so3  = so2 + 128;            // 128
    float* wp1  = so3 + 128;            // 48*10752 = 516096
    unsigned int* h2p = (unsigned int*)(wp1 + 516096);  // 256*339*64 = 5554176 uints
    // total ≈ 6.3M elems ≈ 25 MB

    prep_kernel<<<128, 256, 0, stream>>>(
        conv1_b, bn1_g, bn1_b, bn1_m, bn1_v,
        conv2_w, conv2_b, bn2_g, bn2_b, bn2_m, bn2_v,
        conv3_w, conv3_b, bn3_g, bn3_b, bn3_m, bn3_v,
        fc1_w, w2hi, w2lo, w3hi, w3lo, wp1, so1, so2, so3);

    dim3 g2(BATCH, (L2OUT + TP2 - 1) / TP2);  // (256, 22)
    conv12_kernel<<<g2, 256, 0, stream>>>(x, conv1_w, w2hi, w2lo, so1, so2, h2p);

    tail_kernel<<<BATCH, 512, 0, stream>>>(h2p, w3hi, w3lo, so3, wp1,
                                           fc1_b, fc2_w, fc2_b, fc3_w, fc3_b,
                                           fc4_w, fc4_b, basis, x, (float*)d_out);
}

// Round 6
// 238.353 us; speedup vs baseline: 1.0188x; 1.0188x over previous
//
#include <hip/hip_runtime.h>
#include <math.h>

// ---------------- problem constants ----------------
#define BATCH   256
#define SIGLEN  2048
#define L1OUT   1022   // conv1(2046) -> pool k3 s2
#define L2OUT   339    // conv2(1018) -> pool k3 s3
#define L3OUT   168    // conv3(337)  -> pool k3 s2
#define FCIN    10752  // 64*168

// conv12 tiling: wave = co-tile, 3 pos-tiles, 16x16x32; TP2=16 -> 28.3 KB LDS -> 5 blocks/CU
#define TP2   16
#define NROW  52             // 48 positions + 4 halo
#define H1S   136            // row stride (shorts): 272B rows -> ds_read_b128
#define H1SZ  (NROW*H1S)     // 7072 shorts = 14144 B per plane

// tail kernel: whole-signal conv3 staging, 346 rows x 72 shorts per plane
#define H3R   346

typedef float f32x2  __attribute__((ext_vector_type(2)));
typedef float f32x4  __attribute__((ext_vector_type(4)));
typedef short s16x8  __attribute__((ext_vector_type(8)));

__device__ __forceinline__ unsigned short f2bf(float f) {
    unsigned int u = __float_as_uint(f);
    return (unsigned short)((u + 0x7fffu + ((u >> 16) & 1u)) >> 16);
}
__device__ __forceinline__ float bf2f(unsigned short h) {
    return __uint_as_float(((unsigned int)h) << 16);
}
// packed fp32 FMA (CDNA2+ VOP3P): d = a*b + c on both halves
__device__ __forceinline__ f32x2 pkfma(f32x2 a, f32x2 b, f32x2 c) {
    f32x2 d;
    asm("v_pk_fma_f32 %0, %1, %2, %3" : "=v"(d) : "v"(a), "v"(b), "v"(c));
    return d;
}

// ---------------- prep: weight frag splits + fc1 LDS-transpose permute + BN fold ----------------
__launch_bounds__(256)
__global__ void prep_kernel(
    const float* __restrict__ conv1_b,
    const float* __restrict__ g1, const float* __restrict__ b1,
    const float* __restrict__ m1, const float* __restrict__ v1,
    const float* __restrict__ conv2_w, const float* __restrict__ conv2_b,
    const float* __restrict__ g2, const float* __restrict__ b2,
    const float* __restrict__ m2, const float* __restrict__ v2,
    const float* __restrict__ conv3_w, const float* __restrict__ conv3_b,
    const float* __restrict__ g3, const float* __restrict__ b3,
    const float* __restrict__ m3, const float* __restrict__ v3,
    const float* __restrict__ fc1_w,
    unsigned short* __restrict__ w2hi, unsigned short* __restrict__ w2lo,
    unsigned short* __restrict__ w3hi, unsigned short* __restrict__ w3lo,
    float* __restrict__ wp1,
    float* __restrict__ so1, float* __restrict__ so2, float* __restrict__ so3)
{
    __shared__ float tl[64 * 169];   // transpose tile, stride 169 breaks conflicts

    int t   = threadIdx.x;
    int tid = blockIdx.x * 256 + t;
    int stride = gridDim.x * 256;

    // fc1 permute via LDS: block o (<48) transposes fc1_w[o] (64co x 168u) -> wp1[o][u*64+co]
    if (blockIdx.x < 48) {
        int o = blockIdx.x;
        for (int i = t; i < FCIN; i += 256) {
            int co = i / L3OUT, u = i - co * L3OUT;
            tl[co * 169 + u] = fc1_w[o * FCIN + i];      // coalesced read
        }
        __syncthreads();
        for (int i = t; i < FCIN; i += 256) {
            int u = i >> 6, co = i & 63;
            wp1[o * FCIN + i] = tl[co * 169 + u];        // coalesced write
        }
    }

    // W2 frag (16x16x32): dst = ((k*4 + ci>>5)*64 + co)*32 + (ci&31)
    for (int i = tid; i < 64*128*5; i += stride) {
        int co = i / 640; int rr = i - co*640; int ci = rr / 5; int k = rr - ci*5;
        float w = conv2_w[i];
        unsigned short hi = f2bf(w);
        unsigned short lo = f2bf(w - bf2f(hi));
        int dst = ((k*4 + (ci >> 5))*64 + co)*32 + (ci & 31);
        w2hi[dst] = hi;
        w2lo[dst] = lo;
    }
    // W3 frag (16x16x32): seg s = k*2 + (ci>>5); dst = (s*64 + co)*32 + (ci&31)
    for (int i = tid; i < 64*64*3; i += stride) {
        int co = i / 192; int r = i - co*192; int ci = r / 3; int k = r - ci*3;
        float w = conv3_w[i];
        unsigned short hi = f2bf(w);
        unsigned short lo = f2bf(w - bf2f(hi));
        int dst = ((k*2 + (ci >> 5))*64 + co)*32 + (ci & 31);
        w3hi[dst] = hi;
        w3lo[dst] = lo;
    }
    if (tid < 128) {
        float s = g1[tid] / sqrtf(v1[tid] + 1e-5f);
        so1[tid]       = s;
        so1[128 + tid] = (conv1_b[tid] - m1[tid]) * s + b1[tid];
    }
    if (tid < 64) {
        float s2 = g2[tid] / sqrtf(v2[tid] + 1e-5f);
        so2[tid]      = s2;
        so2[64 + tid] = (conv2_b[tid] - m2[tid]) * s2 + b2[tid];
        float s3 = g3[tid] / sqrtf(v3[tid] + 1e-5f);
        so3[tid]      = s3;
        so3[64 + tid] = (conv3_b[tid] - m3[tid]) * s3 + b3[tid];
    }
}

// ---------------- fused conv1(pk_fma + carry) -> conv2 split-bf16 MFMA ----------------
// (unchanged from round 4 — best measured: ~91 us)
__launch_bounds__(256, 5)
__global__ void conv12_kernel(
    const float* __restrict__ x, const float* __restrict__ w1,
    const unsigned short* __restrict__ w2hi, const unsigned short* __restrict__ w2lo,
    const float* __restrict__ so1, const float* __restrict__ so2,
    unsigned int* __restrict__ h2p)
{
    __shared__ unsigned short h1hi[H1SZ];   // 14144 B; c2 (12480 B) aliases after K-loop
    __shared__ unsigned short h1lo[H1SZ];

    int t  = threadIdx.x;
    int b  = blockIdx.x;
    int u0 = blockIdx.y * TP2;
    int q0 = 3 * u0;
    int wv = __builtin_amdgcn_readfirstlane(t >> 6);
    int l  = t & 63;
    int m  = l & 15;
    int qd = l >> 4;

    // ---- stage 1: conv1 + bn1 + pool + relu, channel-paired pk_fma, carried window ----
    {
        f32x2 wp[9], s1p, o1p;
        const float* wa = w1 + (2*l)*9;
        #pragma unroll
        for (int j = 0; j < 9; ++j) wp[j] = (f32x2){wa[j], wa[9 + j]};
        s1p = (f32x2){so1[2*l], so1[2*l + 1]};
        o1p = (f32x2){so1[128 + 2*l], so1[128 + 2*l + 1]};

        int rbase = 13 * wv;                  // 0,13,26,39 (52 rows total)
        int W0 = 2*(q0 + rbase);              // x window start for first row
        const float* xp0 = x + b*3*SIGLEN;

        f32x2 xb[3][6];                       // broadcast pairs covering [W0 .. W0+5]
        if (W0 + 5 <= SIGLEN - 1) {           // wave-uniform fast path, 8B-aligned
            #pragma unroll
            for (int ci = 0; ci < 3; ++ci) {
                const float* xp = xp0 + ci*SIGLEN + W0;
                float2 v01 = *(const float2*)(xp);
                float2 v23 = *(const float2*)(xp + 2);
                float2 v45 = *(const float2*)(xp + 4);
                xb[ci][0] = (f32x2){v01.x, v01.x};
                xb[ci][1] = (f32x2){v01.y, v01.y};
                xb[ci][2] = (f32x2){v23.x, v23.x};
                xb[ci][3] = (f32x2){v23.y, v23.y};
                xb[ci][4] = (f32x2){v45.x, v45.x};
                xb[ci][5] = (f32x2){v45.y, v45.y};
            }
        } else {
            #pragma unroll
            for (int ci = 0; ci < 3; ++ci)
                #pragma unroll
                for (int j = 0; j < 6; ++j) {
                    int xi = W0 + j; xi = xi < SIGLEN ? xi : SIGLEN - 1;
                    float v = xp0[ci*SIGLEN + xi];
                    xb[ci][j] = (f32x2){v, v};
                }
        }

        f32x2 cr = (f32x2){0.f, 0.f};
        #pragma unroll
        for (int s = 0; s < 13; ++s) {
            int r = rbase + s;
            f32x2 r1 = (f32x2){0.f, 0.f}, r2 = (f32x2){0.f, 0.f};
            #pragma unroll
            for (int ci = 0; ci < 3; ++ci) {
                #pragma unroll
                for (int tp = 0; tp < 3; ++tp) {
                    r1 = pkfma(xb[ci][1 + tp], wp[ci*3 + tp], r1);
                    r2 = pkfma(xb[ci][2 + tp], wp[ci*3 + tp], r2);
                }
            }
            f32x2 r0;
            if (s == 0) {
                r0 = (f32x2){0.f, 0.f};
                #pragma unroll
                for (int ci = 0; ci < 3; ++ci)
                    #pragma unroll
                    for (int tp = 0; tp < 3; ++tp)
                        r0 = pkfma(xb[ci][tp], wp[ci*3 + tp], r0);
            } else {
                r0 = cr;
            }
            cr = r2;

            float m0 = fmaxf(r0[0], fmaxf(r1[0], r2[0]));
            float m1 = fmaxf(r0[1], fmaxf(r1[1], r2[1]));
            float v0 = fmaxf(fmaf(s1p[0], m0, o1p[0]), 0.f);
            float v1 = fmaxf(fmaf(s1p[1], m1, o1p[1]), 0.f);

            // truncation split: hi = top16(v), lo = rne16(v - hi); perm-packed b32 writes.
            unsigned ua = __float_as_uint(v0);
            unsigned ub = __float_as_uint(v1);
            unsigned hipack = __builtin_amdgcn_perm(ub, ua, 0x07060302u);
            float ra = v0 - __uint_as_float(ua & 0xffff0000u);
            float rb = v1 - __uint_as_float(ub & 0xffff0000u);
            unsigned lopack = __builtin_amdgcn_perm(__float_as_uint(rb), __float_as_uint(ra),
                                                    0x07060302u);
            ((unsigned*)h1hi)[r*68 + l] = hipack;   // dword at short-cols {2l, 2l+1}
            ((unsigned*)h1lo)[r*68 + l] = lopack;

            if (s < 12) {
                #pragma unroll
                for (int ci = 0; ci < 3; ++ci) {
                    xb[ci][0] = xb[ci][2]; xb[ci][1] = xb[ci][3];
                    xb[ci][2] = xb[ci][4]; xb[ci][3] = xb[ci][5];
                }
                int Wn = W0 + 2*s + 6;
                if (Wn + 1 <= SIGLEN - 1) {         // wave-uniform, 8B-aligned
                    #pragma unroll
                    for (int ci = 0; ci < 3; ++ci) {
                        float2 v = *(const float2*)(xp0 + ci*SIGLEN + Wn);
                        xb[ci][4] = (f32x2){v.x, v.x};
                        xb[ci][5] = (f32x2){v.y, v.y};
                    }
                } else {
                    #pragma unroll
                    for (int ci = 0; ci < 3; ++ci) {
                        int x4 = Wn     < SIGLEN ? Wn     : SIGLEN - 1;
                        int x5 = Wn + 1 < SIGLEN ? Wn + 1 : SIGLEN - 1;
                        float a4 = xp0[ci*SIGLEN + x4];
                        float a5 = xp0[ci*SIGLEN + x5];
                        xb[ci][4] = (f32x2){a4, a4};
                        xb[ci][5] = (f32x2){a5, a5};
                    }
                }
            }
        }
    }
    __syncthreads();

    // ---- stage 2: 16x16x32 MFMA, wave owns co-tile wv, 3 pos-tiles ----
    f32x4 acc[3] = {(f32x4)(0.f), (f32x4)(0.f), (f32x4)(0.f)};

    const unsigned short* whb = w2hi + wv*512 + m*32 + qd*8;
    const unsigned short* wlb = w2lo + wv*512 + m*32 + qd*8;

    for (int k = 0; k < 5; ++k) {
        #pragma unroll
        for (int cb = 0; cb < 4; ++cb) {
            int st = k*4 + cb;
            s16x8 wh = *(const s16x8*)(whb + st*2048);
            s16x8 wl = *(const s16x8*)(wlb + st*2048);
            #pragma unroll
            for (int pt = 0; pt < 3; ++pt) {
                int row = pt*16 + m + k;   // <= 51
                s16x8 ah = *(const s16x8*)&h1hi[row*H1S + cb*32 + qd*8];
                s16x8 al = *(const s16x8*)&h1lo[row*H1S + cb*32 + qd*8];
                acc[pt] = __builtin_amdgcn_mfma_f32_16x16x32_bf16(ah, wh, acc[pt], 0, 0, 0);
                acc[pt] = __builtin_amdgcn_mfma_f32_16x16x32_bf16(al, wh, acc[pt], 0, 0, 0);
                acc[pt] = __builtin_amdgcn_mfma_f32_16x16x32_bf16(ah, wl, acc[pt], 0, 0, 0);
            }
        }
    }
    __syncthreads();   // all waves done reading h1hi before aliasing as c2

    // D layout: pos = pt*16 + qd*4 + rg, co = wv*16 + m
    float* c2 = (float*)h1hi;   // [48 pos][65]
    #pragma unroll
    for (int pt = 0; pt < 3; ++pt)
        #pragma unroll
        for (int rg = 0; rg < 4; ++rg)
            c2[(pt*16 + qd*4 + rg)*65 + wv*16 + m] = acc[pt][rg];
    __syncthreads();

    // ---- pool(3,3) + bn2 + relu -> h2p[b][u][co] packed bf16 hi|lo (trunc split) ----
    #pragma unroll
    for (int it = 0; it < 4; ++it) {
        int idx = t + it*256;   // < TP2*64 = 1024
        int ul = idx >> 6, co = idx & 63;
        int u = u0 + ul;
        if (u < L2OUT) {
            float v0 = c2[(3*ul  )*65 + co];
            float v1 = c2[(3*ul+1)*65 + co];
            float v2 = c2[(3*ul+2)*65 + co];
            float mm = fmaxf(v0, fmaxf(v1, v2));
            float v  = fmaxf(fmaf(so2[co], mm, so2[64 + co]), 0.f);
            unsigned uu = __float_as_uint(v);
            float rr = v - __uint_as_float(uu & 0xffff0000u);
            h2p[(b*L2OUT + u)*64 + co] = (uu >> 16) | (__float_as_uint(rr) & 0xffff0000u);
        }
    }
}

// ---------------- fused tail: conv3 + pool + bn3 + fc1..fc4 + tanh + integrate + interp ----------------
// One block per batch item (grid 256 = 1 block/CU), 1024 thr = 16 waves (50% occ; LDS-capped
// at 1 block). Staging vectorized 8B/lane (11 iters). conv3: wave = (pt, c4), 18 MFMA/tile.
// fc1: 3 outputs/wave, partials in regs across all 6 tiles. fc chain once. 2 warp points/thread.
__launch_bounds__(1024, 1)
__global__ void tail_kernel(
    const unsigned int* __restrict__ h2p,
    const unsigned short* __restrict__ w3hi, const unsigned short* __restrict__ w3lo,
    const float* __restrict__ so3, const float* __restrict__ wp1,
    const float* __restrict__ fc1_b,
    const float* __restrict__ fc2_w, const float* __restrict__ fc2_b,
    const float* __restrict__ fc3_w, const float* __restrict__ fc3_b,
    const float* __restrict__ fc4_w, const float* __restrict__ fc4_b,
    const float* __restrict__ basis,
    const float* __restrict__ x,
    float* __restrict__ out)
{
    __shared__ unsigned short h3s[2*H3R*72];   // hi plane | lo plane (99.6 KB)
    __shared__ float c3buf[64*65];             // 16.6 KB
    __shared__ float xsr[48];
    __shared__ float xs48[48], hl[32], gl[16], thl[5], Al[12];

    int t  = threadIdx.x;
    int b  = blockIdx.x;
    int wv = __builtin_amdgcn_readfirstlane(t >> 6);   // 0..15
    int l  = t & 63;
    int m  = l & 15;
    int qd = l >> 4;
    int pt = wv >> 2;          // pos-tile 0..3
    int c4 = wv & 3;           // co-quarter

    // ---- stage whole signal: h2p[b] -> hi/lo planes, uint2 (2 co-words) per lane ----
    {
        const unsigned int* src = h2p + (b*L2OUT)*64;
        unsigned* dhi = (unsigned*)h3s;                 // 36 dwords per row
        unsigned* dlo = (unsigned*)(h3s + H3R*72);
        for (int i = t; i < H3R*32; i += 1024) {
            int r = i >> 5, cp = i & 31;
            int g = r > (L2OUT-1) ? (L2OUT-1) : r;
            uint2 v = ((const uint2*)src)[g*32 + cp];   // words for co = 2cp, 2cp+1 (hi|lo<<16)
            dhi[r*36 + cp] = __builtin_amdgcn_perm(v.y, v.x, 0x05040100u);  // hi0 | hi1<<16
            dlo[r*36 + cp] = __builtin_amdgcn_perm(v.y, v.x, 0x07060302u);  // lo0 | lo1<<16
        }
    }

    // conv3 weight frags for this wave's co-quarter (held in regs throughout)
    s16x8 wh[6], wl[6];
    #pragma unroll
    for (int s = 0; s < 6; ++s) {
        wh[s] = *(const s16x8*)(w3hi + s*2048 + (c4*16 + m)*32 + qd*8);
        wl[s] = *(const s16x8*)(w3lo + s*2048 + (c4*16 + m)*32 + qd*8);
    }
    float s3 = so3[l], o3 = so3[64 + l];

    __syncthreads();

    // ---- 6 tiles of 28 pooled outputs; fc1 partials accumulate in regs ----
    int o0 = wv * 3;           // wave's fc1 outputs o0..o0+2
    float fa[3] = {0.f, 0.f, 0.f};

    for (int ti = 0; ti < 6; ++ti) {
        int u0 = ti * 28;

        // conv3 MFMA: wave (pt,c4) does pos-tile pt for co-slice c4
        f32x4 acc = (f32x4)(0.f);
        #pragma unroll
        for (int s = 0; s < 6; ++s) {
            int row = 2*u0 + pt*16 + m + (s >> 1);   // <= 345
            int off = (s & 1)*32 + qd*8;
            s16x8 ah = *(const s16x8*)&h3s[row*72 + off];
            s16x8 al = *(const s16x8*)&h3s[H3R*72 + row*72 + off];
            acc = __builtin_amdgcn_mfma_f32_16x16x32_bf16(ah, wh[s], acc, 0, 0, 0);
            acc = __builtin_amdgcn_mfma_f32_16x16x32_bf16(al, wh[s], acc, 0, 0, 0);
            acc = __builtin_amdgcn_mfma_f32_16x16x32_bf16(ah, wl[s], acc, 0, 0, 0);
        }
        __syncthreads();   // previous tile's c3buf readers done

        #pragma unroll
        for (int rg = 0; rg < 4; ++rg)
            c3buf[(pt*16 + qd*4 + rg)*65 + c4*16 + m] = acc[rg];
        __syncthreads();

        // pool(3,2) + bn3 + relu + fc1 partial for co = l, u = u0..u0+27
        #pragma unroll 4
        for (int u = 0; u < 28; ++u) {
            int p = 2*u;
            float v0 = c3buf[(p  )*65 + l];
            float v1 = c3buf[(p+1)*65 + l];
            float v2 = c3buf[(p+2)*65 + l];
            float pv = fmaxf(fmaf(s3, fmaxf(v0, fmaxf(v1, v2)), o3), 0.f);
            const float* wp = wp1 + (u0 + u)*64 + l;
            #pragma unroll
            for (int j = 0; j < 3; ++j)
                fa[j] = fmaf(pv, wp[(o0 + j)*FCIN], fa[j]);
        }
    }

    // ---- fc1 reduce (over co lanes) ----
    #pragma unroll
    for (int j = 0; j < 3; ++j) {
        #pragma unroll
        for (int off = 32; off > 0; off >>= 1)
            fa[j] += __shfl_xor(fa[j], off, 64);
    }
    if (l == 0) {
        #pragma unroll
        for (int j = 0; j < 3; ++j) xsr[o0 + j] = fa[j];
    }
    __syncthreads();

    // ---- fc chain (once per batch item) ----
    if (t < 48) xs48[t] = fmaxf(xsr[t] + fc1_b[t], 0.f);
    __syncthreads();
    if (t < 32) {
        float sv = fc2_b[t];
        #pragma unroll
        for (int k = 0; k < 48; ++k) sv = fmaf(fc2_w[t * 48 + k], xs48[k], sv);
        hl[t] = fmaxf(sv, 0.f);
    }
    __syncthreads();
    if (t < 16) {
        float sv = fc3_b[t];
        #pragma unroll
        for (int k = 0; k < 32; ++k) sv = fmaf(fc3_w[t * 32 + k], hl[k], sv);
        gl[t] = fmaxf(sv, 0.f);
    }
    __syncthreads();
    if (t < 5) {
        float sv = fc4_b[t];
        #pragma unroll
        for (int k = 0; k < 16; ++k) sv = fmaf(fc4_w[t * 16 + k], gl[k], sv);
        thl[t] = tanhf(sv);
    }
    __syncthreads();
    if (t < 12) {
        float sv = 0.f;
        #pragma unroll
        for (int d = 0; d < 5; ++d) sv = fmaf(basis[t * 5 + d], thl[d], sv);
        Al[t] = sv;
    }
    __syncthreads();

    float a_r[6], b_r[6];
    #pragma unroll
    for (int c = 0; c < 6; ++c) { a_r[c] = Al[2*c]; b_r[c] = Al[2*c+1]; }

    // ---- CPAB integration + interp: 2 points per thread ----
    #pragma unroll
    for (int cc = 0; cc < 2; ++cc) {
        int i = cc * 1024 + t;
        float xp = (float)i / 2047.f;
        float tt = 1.f;
        for (int it = 0; it < 7; ++it) {
            int c = (int)floorf(xp * 6.f);
            c = min(max(c, 0), 5);
            float a  = a_r[c], bb = b_r[c];
            float v  = a * xp + bb;
            float xb = (v >= 0.f) ? (float)(c + 1) / 6.f : (float)c / 6.f;
            bool  big_a = fabsf(a) > 1e-8f;
            float a_s = big_a ? a : 1.f;
            float z   = xp + bb / a_s;
            float zb  = xb + bb / a_s;
            float zden = (fabsf(z) > 1e-12f) ? z : 1e-12f;
            float ratio = zb / zden;
            float t_exp = logf(fmaxf(ratio, 1e-12f)) / a_s;
            float v_s   = (fabsf(v) > 1e-12f) ? v : 1.f;
            float t_lin = (xb - xp) / v_s;
            float thit  = big_a ? t_exp : t_lin;
            bool valid  = (fabsf(v) > 1e-12f) && (thit > 0.f) && ((big_a ? ratio : 1.f) > 0.f);
            if (!valid) thit = __builtin_inff();
            float tau   = fminf(tt, thit);
            float x_new = big_a ? (z * expf(a * tau) - (z - xp)) : (xp + bb * tau);
            bool hit    = (thit <= tt);
            float nudge = (v >= 0.f) ? 1e-6f : -1e-6f;
            xp = hit ? (xb + nudge) : x_new;
            xp = fminf(fmaxf(xp, 0.f), 1.f);
            tt = fmaxf(tt - tau, 0.f);
        }
        float p = fminf(fmaxf(xp, 0.f), 1.f) * 2047.f;
        int i0 = (int)floorf(p);
        i0 = min(max(i0, 0), 2046);
        float w = p - (float)i0;
        #pragma unroll
        for (int c = 0; c < 3; ++c) {
            const float* d = &x[(b * 3 + c) * SIGLEN];
            out[(b * 3 + c) * SIGLEN + i] = d[i0] * (1.f - w) + d[i0 + 1] * w;
        }
    }
}

// ---------------- launch ----------------
extern "C" void kernel_launch(void* const* d_in, const int* in_sizes, int n_in,
                              void* d_out, int out_size, void* d_ws, size_t ws_size,
                              hipStream_t stream) {
    (void)in_sizes; (void)n_in; (void)out_size; (void)ws_size;
    const float* x       = (const float*)d_in[0];
    const float* conv1_w = (const float*)d_in[1];
    const float* conv1_b = (const float*)d_in[2];
    const float* bn1_g   = (const float*)d_in[3];
    const float* bn1_b   = (const float*)d_in[4];
    const float* bn1_m   = (const float*)d_in[5];
    const float* bn1_v   = (const float*)d_in[6];
    const float* conv2_w = (const float*)d_in[7];
    const float* conv2_b = (const float*)d_in[8];
    const float* bn2_g   = (const float*)d_in[9];
    const float* bn2_b   = (const float*)d_in[10];
    const float* bn2_m   = (const float*)d_in[11];
    const float* bn2_v   = (const float*)d_in[12];
    const float* conv3_w = (const float*)d_in[13];
    const float* conv3_b = (const float*)d_in[14];
    const float* bn3_g   = (const float*)d_in[15];
    const float* bn3_b   = (const float*)d_in[16];
    const float* bn3_m   = (const float*)d_in[17];
    const float* bn3_v   = (const float*)d_in[18];
    const float* fc1_w   = (const float*)d_in[19];
    const float* fc1_b   = (const float*)d_in[20];
    const float* fc2_w   = (const float*)d_in[21];
    const float* fc2_b   = (const float*)d_in[22];
    const float* fc3_w   = (const float*)d_in[23];
    const float* fc3_b   = (const float*)d_in[24];
    const float* fc4_w   = (const float*)d_in[25];
    const float* fc4_b   = (const float*)d_in[26];
    const float* basis   = (const float*)d_in[27];

    // workspace layout
    unsigned short* w2hi = (unsigned short*)d_ws;       // 40960 ush
    unsigned short* w2lo = w2hi + 40960;                // 40960 ush
    unsigned short* w3hi = w2lo + 40960;                // 12288 ush
    unsigned short* w3lo = w3hi + 12288;                // 12288 ush
    float* ws   = (float*)d_ws;
    float* so1  = ws + 53248;           // 256
    float* so2  = so1 + 256;            // 128
    float* so3  = so2 + 128;            // 128
    float* wp1  = so3 + 128;            // 48*10752 = 516096
    unsigned int* h2p = (unsigned int*)(wp1 + 516096);  // 256*339*64 = 5554176 uints
    // total ≈ 6.3M elems ≈ 25 MB

    prep_kernel<<<128, 256, 0, stream>>>(
        conv1_b, bn1_g, bn1_b, bn1_m, bn1_v,
        conv2_w, conv2_b, bn2_g, bn2_b, bn2_m, bn2_v,
        conv3_w, conv3_b, bn3_g, bn3_b, bn3_m, bn3_v,
        fc1_w, w2hi, w2lo, w3hi, w3lo, wp1, so1, so2, so3);

    dim3 g2(BATCH, (L2OUT + TP2 - 1) / TP2);  // (256, 22)
    conv12_kernel<<<g2, 256, 0, stream>>>(x, conv1_w, w2hi, w2lo, so1, so2, h2p);

    tail_kernel<<<BATCH, 1024, 0, stream>>>(h2p, w3hi, w3lo, so3, wp1,
                                            fc1_b, fc2_w, fc2_b, fc3_w, fc3_b,
                                            fc4_w, fc4_b, basis, x, (float*)d_out);
}